// Round 1
// baseline (74121.570 us; speedup 1.0000x reference)
//
#include <hip/hip_runtime.h>

// DecoderGRU: 2-layer GRU (B=64, H=1024, T=1024, OUT=128) + output projection.
// Persistent cooperative kernel, software-pipelined across layers:
//   super-step s: L0 computes y0_s | L1 computes y1_{s-1} | PROJ writes out_{s-2}
// Hidden units partitioned across blocks (gates r/z/n for unit j need only
// W rows j, j+H, j+2H). Weights live in LDS as bf16 MFMA B-fragments.
// fp32 master h state in LDS; bf16 copies broadcast via global double buffers.

#define NBLK 200
#define SMEM_BYTES 150208
#define H 1024
#define T 1024

typedef short s16x8 __attribute__((ext_vector_type(8)));
typedef float f32x4 __attribute__((ext_vector_type(4)));

__device__ __forceinline__ unsigned short f2bf(float f) {
  union { float f; unsigned u; } v; v.f = f;
  return (unsigned short)((v.u + 0x7FFFu + ((v.u >> 16) & 1u)) >> 16);
}
__device__ __forceinline__ float sigm(float x) { return 1.f / (1.f + __expf(-x)); }

__device__ __forceinline__ void gridbar(unsigned* ctr, unsigned want) {
  __threadfence();   // release: flush h writes device-scope
  __syncthreads();
  if (threadIdx.x == 0) {
    __hip_atomic_fetch_add(ctr, 1u, __ATOMIC_RELEASE, __HIP_MEMORY_SCOPE_AGENT);
    while (__hip_atomic_load(ctr, __ATOMIC_RELAXED, __HIP_MEMORY_SCOPE_AGENT) < want)
      __builtin_amdgcn_s_sleep(1);
  }
  __syncthreads();
  __threadfence();   // acquire: invalidate before reading peers' h
}

extern "C" __global__ void __launch_bounds__(512, 1)
gru_pipeline(const float* __restrict__ z,
             const float* __restrict__ Whh0,
             const float* __restrict__ bih0, const float* __restrict__ bhh0,
             const float* __restrict__ Wih1, const float* __restrict__ Whh1,
             const float* __restrict__ bih1, const float* __restrict__ bhh1,
             const float* __restrict__ Wout, const float* __restrict__ bout,
             float* __restrict__ out,
             unsigned short* __restrict__ h0buf,   // [2][64*1024] bf16
             unsigned short* __restrict__ h1buf,   // [2][64*1024] bf16
             unsigned* __restrict__ ctr)
{
  extern __shared__ char smem[];
  const int tid  = threadIdx.x;
  const int lane = tid & 63;
  const int w    = tid >> 6;
  const int bid  = blockIdx.x;

  int role, base;
  if (bid < 64)       { role = 0; base = bid * 16; }        // layer 0: 16 units
  else if (bid < 192) { role = 1; base = (bid - 64) * 8; }  // layer 1: 8 units
  else                { role = 2; base = (bid - 192) * 16; }// proj: 16 out cols

  unsigned short* frag = (unsigned short*)smem;

  // ---------------- init: build bf16 B-fragments in LDS, prefill states ----
  if (role == 0) {
    float* bi = (float*)(smem + 114944);
    float* bh = (float*)(smem + 115136);
    float* hm = (float*)(smem + 110848);
    // 48 weight rows (3 gates x 16 units), frag layout: B[k][n], n=lane&15,
    // k = kb*32 + (lane>>4)*8 + j  -> 16B per lane position.
    for (int p = tid; p < 6144; p += 512) {
      int c = p % 48; int r2 = p / 48; int grp = r2 & 3; int kb = r2 >> 2;
      int g = c >> 4, u = c & 15;
      unsigned short* dst = frag + (kb*3 + g)*512 + (grp*16 + u)*8;
      const float* s = Whh0 + (size_t)(g*H + base + u)*H + kb*32 + grp*8;
      #pragma unroll
      for (int j = 0; j < 8; ++j) dst[j] = f2bf(s[j]);
    }
    if (tid < 48) {
      int g = tid >> 4, u = tid & 15;
      bi[tid] = bih0[g*H + base + u];
      bh[tid] = bhh0[g*H + base + u];
    }
    for (int p = tid; p < 1024; p += 512) {
      int b = p >> 4, u = p & 15;
      float v = z[b*H + base + u];
      hm[p] = v;
      h0buf[65536 + b*H + base + u] = f2bf(v);   // y0_{-1} := z
    }
  } else if (role == 1) {
    float* bi = (float*)(smem + 150016);
    float* bh = (float*)(smem + 150112);
    float* hm = (float*)(smem + 147968);
    // two GEMMs (ih over x=y0, hh over h1): 24 real cols each, padded to 32
    for (int p = tid; p < 8192; p += 512) {
      int c = p & 31, grp = (p >> 5) & 3, kb = (p >> 7) & 31, gm = p >> 12;
      unsigned short* dst = frag + gm*32768 + (kb*2 + (c>>4))*512 + (grp*16 + (c&15))*8;
      if (c < 24) {
        int g = c >> 3, u = c & 7;
        const float* W = gm ? Whh1 : Wih1;
        const float* s = W + (size_t)(g*H + base + u)*H + kb*32 + grp*8;
        #pragma unroll
        for (int j = 0; j < 8; ++j) dst[j] = f2bf(s[j]);
      } else {
        #pragma unroll
        for (int j = 0; j < 8; ++j) dst[j] = 0;
      }
    }
    if (tid < 24) {
      int g = tid >> 3, u = tid & 7;
      bi[tid] = bih1[g*H + base + u];
      bh[tid] = bhh1[g*H + base + u];
    }
    {
      int b = tid >> 3, u = tid & 7;
      float v = z[b*H + base + u];
      hm[tid] = v;
      h1buf[65536 + b*H + base + u] = f2bf(v);   // y1_{-1} := z
    }
  } else {
    float* bo = (float*)(smem + 32768);
    for (int p = tid; p < 2048; p += 512) {
      int c = p & 15, grp = (p >> 4) & 3, kb = p >> 6;
      unsigned short* dst = frag + kb*512 + (grp*16 + c)*8;
      const float* s = Wout + (size_t)(base + c)*H + kb*32 + grp*8;
      #pragma unroll
      for (int j = 0; j < 8; ++j) dst[j] = f2bf(s[j]);
    }
    if (tid < 16) bo[tid] = bout[base + tid];
  }

  unsigned phase = 1;
  gridbar(ctr, NBLK * phase); ++phase;

  // ---------------- pipelined recurrence ----------------
  for (int s = 0; s < 1026; ++s, ++phase) {
    if (role == 0) {
      if (s < 1024) {
        const int t = s;
        float* G  = (float*)(smem + 98304);
        float* hm = (float*)(smem + 110848);
        float* bi = (float*)(smem + 114944);
        float* bh = (float*)(smem + 115136);
        if (w < 4) {   // waves 0-3: one M-tile each, N=48 (3 tiles), K=1024
          const unsigned short* src  = h0buf + ((t+1)&1)*65536;
          const unsigned short* arow = src + (w*16 + (lane&15))*H + ((lane>>4)*8);
          const unsigned short* bb   = frag + lane*8;
          f32x4 a0 = {0,0,0,0}, a1 = {0,0,0,0}, a2 = {0,0,0,0};
          #pragma unroll 8
          for (int kb = 0; kb < 32; ++kb) {
            s16x8 av = *(const s16x8*)(arow + kb*32);
            s16x8 b0 = *(const s16x8*)(bb + (kb*3+0)*512);
            s16x8 b1 = *(const s16x8*)(bb + (kb*3+1)*512);
            s16x8 b2 = *(const s16x8*)(bb + (kb*3+2)*512);
            a0 = __builtin_amdgcn_mfma_f32_16x16x32_bf16(av, b0, a0, 0, 0, 0);
            a1 = __builtin_amdgcn_mfma_f32_16x16x32_bf16(av, b1, a1, 0, 0, 0);
            a2 = __builtin_amdgcn_mfma_f32_16x16x32_bf16(av, b2, a2, 0, 0, 0);
          }
          int col = lane & 15, r0 = (lane >> 4) * 4;
          #pragma unroll
          for (int r = 0; r < 4; ++r) {
            int brow = w*16 + r0 + r;
            G[brow*49 +      col] = a0[r];
            G[brow*49 + 16 + col] = a1[r];
            G[brow*49 + 32 + col] = a2[r];
          }
        }
        __syncthreads();
        #pragma unroll
        for (int q = 0; q < 2; ++q) {   // 1024 (b,u) pairs over 512 threads
          int idx = tid + q*512;
          int b = idx >> 4, u = idx & 15;
          float hr = G[b*49 + u]      + bh[u];
          float hz = G[b*49 + 16 + u] + bh[16 + u];
          float hn = G[b*49 + 32 + u] + bh[32 + u];
          float r  = sigm(bi[u] + hr);         // gx = b_ih_0 (x==0)
          float zg = sigm(bi[16 + u] + hz);
          float n  = tanhf(bi[32 + u] + r * hn);
          float hp = hm[idx];
          float hv = (1.f - zg) * n + zg * hp;
          hm[idx] = hv;
          h0buf[(t&1)*65536 + b*H + base + u] = f2bf(hv);
        }
      }
    } else if (role == 1) {
      if (s >= 1 && s <= 1024) {
        const int t = s - 1;
        float* Gx = (float*)(smem + 131072);
        float* Gh = (float*)(smem + 139520);
        float* hm = (float*)(smem + 147968);
        float* bi = (float*)(smem + 150016);
        float* bh = (float*)(smem + 150112);
        {
          const int mt  = w & 3;
          const int isx = (w < 4);    // waves 0-3: gx GEMM, 4-7: gh GEMM
          const unsigned short* src  = isx ? (h0buf + (t&1)*65536)
                                           : (h1buf + ((t+1)&1)*65536);
          const unsigned short* arow = src + (mt*16 + (lane&15))*H + ((lane>>4)*8);
          const unsigned short* bb   = frag + (isx ? 0 : 32768) + lane*8;
          f32x4 a0 = {0,0,0,0}, a1 = {0,0,0,0};
          #pragma unroll 8
          for (int kb = 0; kb < 32; ++kb) {
            s16x8 av = *(const s16x8*)(arow + kb*32);
            s16x8 b0 = *(const s16x8*)(bb + (kb*2+0)*512);
            s16x8 b1 = *(const s16x8*)(bb + (kb*2+1)*512);
            a0 = __builtin_amdgcn_mfma_f32_16x16x32_bf16(av, b0, a0, 0, 0, 0);
            a1 = __builtin_amdgcn_mfma_f32_16x16x32_bf16(av, b1, a1, 0, 0, 0);
          }
          float* G = isx ? Gx : Gh;
          int col = lane & 15, r0 = (lane >> 4) * 4;
          #pragma unroll
          for (int r = 0; r < 4; ++r) {
            int brow = mt*16 + r0 + r;
            G[brow*33 +      col] = a0[r];
            G[brow*33 + 16 + col] = a1[r];
          }
        }
        __syncthreads();
        {
          int b = tid >> 3, u = tid & 7;
          float xr = Gx[b*33 + u]      + bi[u];
          float xz = Gx[b*33 + 8 + u]  + bi[8 + u];
          float xn = Gx[b*33 + 16 + u] + bi[16 + u];
          float hr = Gh[b*33 + u]      + bh[u];
          float hz = Gh[b*33 + 8 + u]  + bh[8 + u];
          float hn = Gh[b*33 + 16 + u] + bh[16 + u];
          float r  = sigm(xr + hr);
          float zg = sigm(xz + hz);
          float n  = tanhf(xn + r * hn);
          float hp = hm[tid];
          float hv = (1.f - zg) * n + zg * hp;
          hm[tid] = hv;
          h1buf[(t&1)*65536 + b*H + base + u] = f2bf(hv);
        }
      }
    } else {
      if (s >= 2) {
        const int t = s - 2;
        float* bo = (float*)(smem + 32768);
        if (w < 4) {
          const unsigned short* src  = h1buf + (t&1)*65536;
          const unsigned short* arow = src + (w*16 + (lane&15))*H + ((lane>>4)*8);
          const unsigned short* bb   = frag + lane*8;
          f32x4 a0 = {0,0,0,0};
          #pragma unroll 8
          for (int kb = 0; kb < 32; ++kb) {
            s16x8 av = *(const s16x8*)(arow + kb*32);
            s16x8 b0 = *(const s16x8*)(bb + kb*512);
            a0 = __builtin_amdgcn_mfma_f32_16x16x32_bf16(av, b0, a0, 0, 0, 0);
          }
          int col = lane & 15, r0 = (lane >> 4) * 4;
          #pragma unroll
          for (int r = 0; r < 4; ++r) {
            int brow = w*16 + r0 + r;
            out[(size_t)(brow*T + t)*128 + base + col] = a0[r] + bo[col];
          }
        }
      }
    }
    gridbar(ctr, NBLK * phase);
  }
}

extern "C" void kernel_launch(void* const* d_in, const int* in_sizes, int n_in,
                              void* d_out, int out_size, void* d_ws, size_t ws_size,
                              hipStream_t stream) {
  const float* z    = (const float*)d_in[0];
  // d_in[1] = seq_len (==1024, hard-coded); d_in[2] = W_ih_0 (unused: x0==0)
  const float* Whh0 = (const float*)d_in[3];
  const float* bih0 = (const float*)d_in[4];
  const float* bhh0 = (const float*)d_in[5];
  const float* Wih1 = (const float*)d_in[6];
  const float* Whh1 = (const float*)d_in[7];
  const float* bih1 = (const float*)d_in[8];
  const float* bhh1 = (const float*)d_in[9];
  const float* Wout = (const float*)d_in[10];
  const float* bout = (const float*)d_in[11];
  float* out = (float*)d_out;

  unsigned* ctr = (unsigned*)d_ws;
  unsigned short* h0buf = (unsigned short*)((char*)d_ws + 1024);
  unsigned short* h1buf = (unsigned short*)((char*)d_ws + 1024 + 2*65536*2);

  hipFuncSetAttribute((const void*)gru_pipeline,
                      hipFuncAttributeMaxDynamicSharedMemorySize, SMEM_BYTES);
  hipMemsetAsync(d_ws, 0, 1024, stream);   // barrier counter (ws is poisoned)

  void* args[] = { (void*)&z, (void*)&Whh0, (void*)&bih0, (void*)&bhh0,
                   (void*)&Wih1, (void*)&Whh1, (void*)&bih1, (void*)&bhh1,
                   (void*)&Wout, (void*)&bout, (void*)&out,
                   (void*)&h0buf, (void*)&h1buf, (void*)&ctr };
  hipLaunchCooperativeKernel((void*)gru_pipeline, dim3(NBLK), dim3(512),
                             args, SMEM_BYTES, stream);
}

// Round 2
// 16527.066 us; speedup vs baseline: 4.4849x; 4.4849x over previous
//
#include <hip/hip_runtime.h>

// DecoderGRU: 2-layer GRU (B=64, H=1024, T=1024, OUT=128) + output projection.
// Persistent cooperative kernel, software-pipelined across layers:
//   super-step s: L0 computes y0_s | L1 computes y1_{s-1} | PROJ writes out_{s-2}
// R2 change: fence-free cross-XCD sync. All h traffic uses relaxed agent-scope
// atomics (-> sc1, bypass non-coherent per-XCD L2, served by Infinity Cache).
// Barrier = 25 padded arrive counters + separate epoch broadcast word. The R1
// version's __threadfence() pair per block per step compiled to L2-wide
// wbl2/inv -> 72us/step of cache maintenance; this removes it entirely.

#define NBLK 200
#define SMEM_BYTES 150208
#define H 1024
#define T 1024

typedef short s16x8 __attribute__((ext_vector_type(8)));
typedef float f32x4 __attribute__((ext_vector_type(4)));
typedef unsigned long long u64;

__device__ __forceinline__ unsigned short f2bf(float f) {
  union { float f; unsigned u; } v; v.f = f;
  return (unsigned short)((v.u + 0x7FFFu + ((v.u >> 16) & 1u)) >> 16);
}
__device__ __forceinline__ float sigm(float x) { return 1.f / (1.f + __expf(-x)); }

// device-scope (sc1) helpers — relaxed atomics, no fence instructions
__device__ __forceinline__ u64 ld_u64(const void* p) {
  return __hip_atomic_load((const u64*)p, __ATOMIC_RELAXED, __HIP_MEMORY_SCOPE_AGENT);
}
__device__ __forceinline__ void st_u32(void* p, unsigned v) {
  __hip_atomic_store((unsigned*)p, v, __ATOMIC_RELAXED, __HIP_MEMORY_SCOPE_AGENT);
}
__device__ __forceinline__ void st_u16(void* p, unsigned short v) {
  __hip_atomic_store((unsigned short*)p, v, __ATOMIC_RELAXED, __HIP_MEMORY_SCOPE_AGENT);
}
__device__ __forceinline__ s16x8 ld_a16(const unsigned short* p) {
  union { u64 q[2]; s16x8 v; } u;
  u.q[0] = ld_u64(p);
  u.q[1] = ld_u64(p + 4);
  return u.v;
}

// Grid barrier: arrive on ctr[group] (25 groups x 8 blocks, 128B-spaced lines),
// block 0 wave 0 scans all groups with one vector load + ballot, then writes
// epoch; everyone else spins (read-only) on epoch. No fences: h data moves via
// sc1 atomics, __syncthreads drains vmcnt(0) before the arrive-add issues.
__device__ __forceinline__ void gridbar(unsigned* ctr, unsigned* epoch,
                                        unsigned phase, int tid, int lane,
                                        int w, int bid) {
  __syncthreads();
  if (tid == 0)
    __hip_atomic_fetch_add(ctr + (bid >> 3) * 32, 1u,
                           __ATOMIC_RELAXED, __HIP_MEMORY_SCOPE_AGENT);
  if (bid == 0) {
    if (w == 0) {
      const unsigned tgt = 8u * phase;
      unsigned* c = ctr + (lane < 25 ? lane : 0) * 32;
      for (;;) {
        unsigned v0 = __hip_atomic_load(c, __ATOMIC_RELAXED, __HIP_MEMORY_SCOPE_AGENT);
        unsigned v = (lane < 25) ? v0 : tgt;
        if (__ballot(v < tgt) == 0ull) break;
        __builtin_amdgcn_s_sleep(1);
      }
      if (lane == 0)
        __hip_atomic_store(epoch, phase, __ATOMIC_RELAXED, __HIP_MEMORY_SCOPE_AGENT);
    }
  } else if (tid == 0) {
    while (__hip_atomic_load(epoch, __ATOMIC_RELAXED, __HIP_MEMORY_SCOPE_AGENT) < phase)
      __builtin_amdgcn_s_sleep(1);
  }
  __syncthreads();
}

extern "C" __global__ void __launch_bounds__(512, 1)
gru_pipeline(const float* __restrict__ z,
             const float* __restrict__ Whh0,
             const float* __restrict__ bih0, const float* __restrict__ bhh0,
             const float* __restrict__ Wih1, const float* __restrict__ Whh1,
             const float* __restrict__ bih1, const float* __restrict__ bhh1,
             const float* __restrict__ Wout, const float* __restrict__ bout,
             float* __restrict__ out,
             unsigned short* __restrict__ h0buf,   // [2][64*1024] bf16
             unsigned short* __restrict__ h1buf,   // [2][64*1024] bf16
             unsigned* __restrict__ ctr,           // 25 x 128B-spaced counters
             unsigned* __restrict__ epoch)
{
  extern __shared__ char smem[];
  const int tid  = threadIdx.x;
  const int lane = tid & 63;
  const int w    = tid >> 6;
  const int bid  = blockIdx.x;

  int role, base;
  if (bid < 64)       { role = 0; base = bid * 16; }        // layer 0: 16 units
  else if (bid < 192) { role = 1; base = (bid - 64) * 8; }  // layer 1: 8 units
  else                { role = 2; base = (bid - 192) * 16; }// proj: 16 out cols

  unsigned short* frag = (unsigned short*)smem;

  // ---------------- init: build bf16 B-fragments in LDS, prefill states ----
  if (role == 0) {
    float* bi = (float*)(smem + 114944);
    float* bh = (float*)(smem + 115136);
    float* hm = (float*)(smem + 110848);
    for (int p = tid; p < 6144; p += 512) {
      int c = p % 48; int r2 = p / 48; int grp = r2 & 3; int kb = r2 >> 2;
      int g = c >> 4, u = c & 15;
      unsigned short* dst = frag + (kb*3 + g)*512 + (grp*16 + u)*8;
      const float* s = Whh0 + (size_t)(g*H + base + u)*H + kb*32 + grp*8;
      #pragma unroll
      for (int j = 0; j < 8; ++j) dst[j] = f2bf(s[j]);
    }
    if (tid < 48) {
      int g = tid >> 4, u = tid & 15;
      bi[tid] = bih0[g*H + base + u];
      bh[tid] = bhh0[g*H + base + u];
    }
    for (int p = tid; p < 1024; p += 512) {
      int b = p >> 4, u = p & 15;
      float v = z[b*H + base + u];
      hm[p] = v;
      st_u16(&h0buf[65536 + b*H + base + u], f2bf(v));   // y0_{-1} := z
    }
  } else if (role == 1) {
    float* bi = (float*)(smem + 150016);
    float* bh = (float*)(smem + 150112);
    float* hm = (float*)(smem + 147968);
    for (int p = tid; p < 8192; p += 512) {
      int c = p & 31, grp = (p >> 5) & 3, kb = (p >> 7) & 31, gm = p >> 12;
      unsigned short* dst = frag + gm*32768 + (kb*2 + (c>>4))*512 + (grp*16 + (c&15))*8;
      if (c < 24) {
        int g = c >> 3, u = c & 7;
        const float* W = gm ? Whh1 : Wih1;
        const float* s = W + (size_t)(g*H + base + u)*H + kb*32 + grp*8;
        #pragma unroll
        for (int j = 0; j < 8; ++j) dst[j] = f2bf(s[j]);
      } else {
        #pragma unroll
        for (int j = 0; j < 8; ++j) dst[j] = 0;
      }
    }
    if (tid < 24) {
      int g = tid >> 3, u = tid & 7;
      bi[tid] = bih1[g*H + base + u];
      bh[tid] = bhh1[g*H + base + u];
    }
    {
      int b = tid >> 3, u = tid & 7;
      float v = z[b*H + base + u];
      hm[tid] = v;
      st_u16(&h1buf[65536 + b*H + base + u], f2bf(v));   // y1_{-1} := z
    }
  } else {
    float* bo = (float*)(smem + 32768);
    for (int p = tid; p < 2048; p += 512) {
      int c = p & 15, grp = (p >> 4) & 3, kb = p >> 6;
      unsigned short* dst = frag + kb*512 + (grp*16 + c)*8;
      const float* s = Wout + (size_t)(base + c)*H + kb*32 + grp*8;
      #pragma unroll
      for (int j = 0; j < 8; ++j) dst[j] = f2bf(s[j]);
    }
    if (tid < 16) bo[tid] = bout[base + tid];
  }

  unsigned phase = 1;
  gridbar(ctr, epoch, phase, tid, lane, w, bid); ++phase;

  // ---------------- pipelined recurrence ----------------
  for (int s = 0; s < 1026; ++s, ++phase) {
    if (role == 0) {
      if (s < 1024) {
        const int t = s;
        float* G  = (float*)(smem + 98304);
        float* hm = (float*)(smem + 110848);
        float* bi = (float*)(smem + 114944);
        float* bh = (float*)(smem + 115136);
        if (w < 4) {   // waves 0-3: one M-tile each, N=48 (3 tiles), K=1024
          const unsigned short* src  = h0buf + ((t+1)&1)*65536;
          const unsigned short* arow = src + (w*16 + (lane&15))*H + ((lane>>4)*8);
          const unsigned short* bb   = frag + lane*8;
          f32x4 a0 = {0,0,0,0}, a1 = {0,0,0,0}, a2 = {0,0,0,0};
          #pragma unroll 8
          for (int kb = 0; kb < 32; ++kb) {
            s16x8 av = ld_a16(arow + kb*32);
            s16x8 b0 = *(const s16x8*)(bb + (kb*3+0)*512);
            s16x8 b1 = *(const s16x8*)(bb + (kb*3+1)*512);
            s16x8 b2 = *(const s16x8*)(bb + (kb*3+2)*512);
            a0 = __builtin_amdgcn_mfma_f32_16x16x32_bf16(av, b0, a0, 0, 0, 0);
            a1 = __builtin_amdgcn_mfma_f32_16x16x32_bf16(av, b1, a1, 0, 0, 0);
            a2 = __builtin_amdgcn_mfma_f32_16x16x32_bf16(av, b2, a2, 0, 0, 0);
          }
          int col = lane & 15, r0 = (lane >> 4) * 4;
          #pragma unroll
          for (int r = 0; r < 4; ++r) {
            int brow = w*16 + r0 + r;
            G[brow*49 +      col] = a0[r];
            G[brow*49 + 16 + col] = a1[r];
            G[brow*49 + 32 + col] = a2[r];
          }
        }
        __syncthreads();
        {
          int b = tid >> 3, u2 = (tid & 7) * 2;
          unsigned short pk[2];
          #pragma unroll
          for (int j = 0; j < 2; ++j) {
            int u = u2 + j;
            float hr = G[b*49 + u]      + bh[u];
            float hz = G[b*49 + 16 + u] + bh[16 + u];
            float hn = G[b*49 + 32 + u] + bh[32 + u];
            float r  = sigm(bi[u] + hr);         // gx = b_ih_0 (x==0)
            float zg = sigm(bi[16 + u] + hz);
            float n  = tanhf(bi[32 + u] + r * hn);
            int idx = b*16 + u;
            float hp = hm[idx];
            float hv = (1.f - zg) * n + zg * hp;
            hm[idx] = hv;
            pk[j] = f2bf(hv);
          }
          st_u32(&h0buf[(t&1)*65536 + b*H + base + u2],
                 (unsigned)pk[0] | ((unsigned)pk[1] << 16));
        }
      }
    } else if (role == 1) {
      if (s >= 1 && s <= 1024) {
        const int t = s - 1;
        float* Gx = (float*)(smem + 131072);
        float* Gh = (float*)(smem + 139520);
        float* hm = (float*)(smem + 147968);
        float* bi = (float*)(smem + 150016);
        float* bh = (float*)(smem + 150112);
        {
          const int mt  = w & 3;
          const int isx = (w < 4);    // waves 0-3: gx GEMM, 4-7: gh GEMM
          const unsigned short* src  = isx ? (h0buf + (t&1)*65536)
                                           : (h1buf + ((t+1)&1)*65536);
          const unsigned short* arow = src + (mt*16 + (lane&15))*H + ((lane>>4)*8);
          const unsigned short* bb   = frag + (isx ? 0 : 32768) + lane*8;
          f32x4 a0 = {0,0,0,0}, a1 = {0,0,0,0};
          #pragma unroll 8
          for (int kb = 0; kb < 32; ++kb) {
            s16x8 av = ld_a16(arow + kb*32);
            s16x8 b0 = *(const s16x8*)(bb + (kb*2+0)*512);
            s16x8 b1 = *(const s16x8*)(bb + (kb*2+1)*512);
            a0 = __builtin_amdgcn_mfma_f32_16x16x32_bf16(av, b0, a0, 0, 0, 0);
            a1 = __builtin_amdgcn_mfma_f32_16x16x32_bf16(av, b1, a1, 0, 0, 0);
          }
          float* G = isx ? Gx : Gh;
          int col = lane & 15, r0 = (lane >> 4) * 4;
          #pragma unroll
          for (int r = 0; r < 4; ++r) {
            int brow = mt*16 + r0 + r;
            G[brow*33 +      col] = a0[r];
            G[brow*33 + 16 + col] = a1[r];
          }
        }
        __syncthreads();
        if (tid < 256) {
          int b = tid >> 2, u2 = (tid & 3) * 2;
          unsigned short pk[2];
          #pragma unroll
          for (int j = 0; j < 2; ++j) {
            int u = u2 + j;
            float xr = Gx[b*33 + u]      + bi[u];
            float xz = Gx[b*33 + 8 + u]  + bi[8 + u];
            float xn = Gx[b*33 + 16 + u] + bi[16 + u];
            float hr = Gh[b*33 + u]      + bh[u];
            float hz = Gh[b*33 + 8 + u]  + bh[8 + u];
            float hn = Gh[b*33 + 16 + u] + bh[16 + u];
            float r  = sigm(xr + hr);
            float zg = sigm(xz + hz);
            float n  = tanhf(xn + r * hn);
            int idx = b*8 + u;
            float hp = hm[idx];
            float hv = (1.f - zg) * n + zg * hp;
            hm[idx] = hv;
            pk[j] = f2bf(hv);
          }
          st_u32(&h1buf[(t&1)*65536 + b*H + base + u2],
                 (unsigned)pk[0] | ((unsigned)pk[1] << 16));
        }
      }
    } else {
      if (s >= 2) {
        const int t = s - 2;
        float* bo = (float*)(smem + 32768);
        if (w < 4) {
          const unsigned short* src  = h1buf + (t&1)*65536;
          const unsigned short* arow = src + (w*16 + (lane&15))*H + ((lane>>4)*8);
          const unsigned short* bb   = frag + lane*8;
          f32x4 a0 = {0,0,0,0};
          #pragma unroll 8
          for (int kb = 0; kb < 32; ++kb) {
            s16x8 av = ld_a16(arow + kb*32);
            s16x8 b0 = *(const s16x8*)(bb + kb*512);
            a0 = __builtin_amdgcn_mfma_f32_16x16x32_bf16(av, b0, a0, 0, 0, 0);
          }
          int col = lane & 15, r0 = (lane >> 4) * 4;
          #pragma unroll
          for (int r = 0; r < 4; ++r) {
            int brow = w*16 + r0 + r;
            out[(size_t)(brow*T + t)*128 + base + col] = a0[r] + bo[col];
          }
        }
      }
    }
    gridbar(ctr, epoch, phase, tid, lane, w, bid);
  }
}

extern "C" void kernel_launch(void* const* d_in, const int* in_sizes, int n_in,
                              void* d_out, int out_size, void* d_ws, size_t ws_size,
                              hipStream_t stream) {
  const float* z    = (const float*)d_in[0];
  // d_in[1] = seq_len (==1024, hard-coded); d_in[2] = W_ih_0 (unused: x0==0)
  const float* Whh0 = (const float*)d_in[3];
  const float* bih0 = (const float*)d_in[4];
  const float* bhh0 = (const float*)d_in[5];
  const float* Wih1 = (const float*)d_in[6];
  const float* Whh1 = (const float*)d_in[7];
  const float* bih1 = (const float*)d_in[8];
  const float* bhh1 = (const float*)d_in[9];
  const float* Wout = (const float*)d_in[10];
  const float* bout = (const float*)d_in[11];
  float* out = (float*)d_out;

  unsigned* ctr   = (unsigned*)d_ws;                       // 25 x 128B lines
  unsigned* epoch = (unsigned*)((char*)d_ws + 4096);       // own line
  unsigned short* h0buf = (unsigned short*)((char*)d_ws + 8192);
  unsigned short* h1buf = (unsigned short*)((char*)d_ws + 8192 + 2*65536*2);

  hipFuncSetAttribute((const void*)gru_pipeline,
                      hipFuncAttributeMaxDynamicSharedMemorySize, SMEM_BYTES);
  hipMemsetAsync(d_ws, 0, 8192, stream);   // counters + epoch (ws is poisoned)

  void* args[] = { (void*)&z, (void*)&Whh0, (void*)&bih0, (void*)&bhh0,
                   (void*)&Wih1, (void*)&Whh1, (void*)&bih1, (void*)&bhh1,
                   (void*)&Wout, (void*)&bout, (void*)&out,
                   (void*)&h0buf, (void*)&h1buf, (void*)&ctr, (void*)&epoch };
  hipLaunchCooperativeKernel((void*)gru_pipeline, dim3(NBLK), dim3(512),
                             args, SMEM_BYTES, stream);
}

// Round 3
// 12870.532 us; speedup vs baseline: 5.7590x; 1.2841x over previous
//
#include <hip/hip_runtime.h>

// DecoderGRU: 2-layer GRU (B=64, H=1024, T=1024, OUT=128) + output projection.
// Persistent cooperative kernel, software-pipelined across layers:
//   super-step s: L0 computes y0_s | L1 computes y1_{s-1} | PROJ writes out_{s-2}
// R3: h traffic moved from per-lane 8B atomics (uncoalesced fabric transactions,
// ~5.4M/step) to coalesced global_load/store_dwordx4 with sc0+sc1 (device-
// coherent, served by memory-side Infinity Cache, 64B line requests). Manual
// 16-deep load pipelining with explicit vmcnt waits. Dedicated coordinator
// block (200) runs the barrier scan so no compute block gates epoch publish.

#define NWORK 200
#define NBLK 201
#define SMEM_BYTES 150208
#define H 1024
#define T 1024

typedef short s16x8 __attribute__((ext_vector_type(8)));
typedef float f32x4 __attribute__((ext_vector_type(4)));
typedef unsigned long long u64;

__device__ __forceinline__ unsigned short f2bf(float f) {
  union { float f; unsigned u; } v; v.f = f;
  return (unsigned short)((v.u + 0x7FFFu + ((v.u >> 16) & 1u)) >> 16);
}
__device__ __forceinline__ float sigm(float x) { return 1.f / (1.f + __expf(-x)); }

__device__ __forceinline__ void st_u16(void* p, unsigned short v) {
  __hip_atomic_store((unsigned short*)p, v, __ATOMIC_RELAXED, __HIP_MEMORY_SCOPE_AGENT);
}

// ---- coalesced device-coherent 16B load/store (bypass L1/L2 -> IF$) ----
#define GLD(d, p, off) \
  asm volatile("global_load_dwordx4 %0, %1, off offset:" #off " sc0 sc1" \
               : "=v"(d) : "v"(p))
#define GLD16A(A, p) \
  GLD(A[0],p,0);    GLD(A[1],p,64);   GLD(A[2],p,128);  GLD(A[3],p,192);  \
  GLD(A[4],p,256);  GLD(A[5],p,320);  GLD(A[6],p,384);  GLD(A[7],p,448);  \
  GLD(A[8],p,512);  GLD(A[9],p,576);  GLD(A[10],p,640); GLD(A[11],p,704); \
  GLD(A[12],p,768); GLD(A[13],p,832); GLD(A[14],p,896); GLD(A[15],p,960)
#define GLD16B(A, p) \
  GLD(A[0],p,1024); GLD(A[1],p,1088); GLD(A[2],p,1152); GLD(A[3],p,1216); \
  GLD(A[4],p,1280); GLD(A[5],p,1344); GLD(A[6],p,1408); GLD(A[7],p,1472); \
  GLD(A[8],p,1536); GLD(A[9],p,1600); GLD(A[10],p,1664); GLD(A[11],p,1728); \
  GLD(A[12],p,1792); GLD(A[13],p,1856); GLD(A[14],p,1920); GLD(A[15],p,1984)
#define WAITV(n) asm volatile("s_waitcnt vmcnt(" #n ")" ::: "memory")
#define TIE16(A) \
  asm volatile("" : "+v"(A[0]),"+v"(A[1]),"+v"(A[2]),"+v"(A[3]), \
                    "+v"(A[4]),"+v"(A[5]),"+v"(A[6]),"+v"(A[7]), \
                    "+v"(A[8]),"+v"(A[9]),"+v"(A[10]),"+v"(A[11]), \
                    "+v"(A[12]),"+v"(A[13]),"+v"(A[14]),"+v"(A[15]))

__device__ __forceinline__ void gst16(s16x8 v, void* p) {
  asm volatile("global_store_dwordx4 %0, %1, off sc0 sc1" :: "v"(p), "v"(v) : "memory");
}

// Worker barrier: drain own device-coherent stores, arrive on group counter,
// thread 0 spins on the (read-only) epoch line published by the coordinator.
__device__ __forceinline__ void bar_worker(unsigned* ctr, unsigned* epoch,
                                           unsigned phase, int tid, int bid) {
  WAITV(0);
  __syncthreads();
  if (tid == 0) {
    __hip_atomic_fetch_add(ctr + (bid >> 3) * 32, 1u,
                           __ATOMIC_RELAXED, __HIP_MEMORY_SCOPE_AGENT);
    while (__hip_atomic_load(epoch, __ATOMIC_RELAXED, __HIP_MEMORY_SCOPE_AGENT) < phase)
      __builtin_amdgcn_s_sleep(1);
  }
  __syncthreads();
}

extern "C" __global__ void __launch_bounds__(512, 2)
gru_pipeline(const float* __restrict__ z,
             const float* __restrict__ Whh0,
             const float* __restrict__ bih0, const float* __restrict__ bhh0,
             const float* __restrict__ Wih1, const float* __restrict__ Whh1,
             const float* __restrict__ bih1, const float* __restrict__ bhh1,
             const float* __restrict__ Wout, const float* __restrict__ bout,
             float* __restrict__ out,
             unsigned short* __restrict__ h0buf,   // [2][64*1024] bf16
             unsigned short* __restrict__ h1buf,   // [2][64*1024] bf16
             unsigned* __restrict__ ctr,           // 25 x 128B-spaced counters
             unsigned* __restrict__ epoch)
{
  extern __shared__ char smem[];
  const int tid  = threadIdx.x;
  const int lane = tid & 63;
  const int w    = tid >> 6;
  const int bid  = blockIdx.x;

  // ---------------- coordinator block: barrier engine only ----------------
  if (bid == NWORK) {
    if (w == 0) {
      for (unsigned phase = 1; phase <= 1027; ++phase) {
        const unsigned tgt = 8u * phase;
        unsigned* c = ctr + (lane < 25 ? lane : 0) * 32;
        for (;;) {
          unsigned v0 = __hip_atomic_load(c, __ATOMIC_RELAXED, __HIP_MEMORY_SCOPE_AGENT);
          unsigned v = (lane < 25) ? v0 : tgt;
          if (__ballot(v < tgt) == 0ull) break;
          __builtin_amdgcn_s_sleep(2);
        }
        if (lane == 0)
          __hip_atomic_store(epoch, phase, __ATOMIC_RELAXED, __HIP_MEMORY_SCOPE_AGENT);
      }
    }
    return;
  }

  int role, base;
  if (bid < 64)       { role = 0; base = bid * 16; }        // layer 0: 16 units
  else if (bid < 192) { role = 1; base = (bid - 64) * 8; }  // layer 1: 8 units
  else                { role = 2; base = (bid - 192) * 16; }// proj: 16 out cols

  unsigned short* frag = (unsigned short*)smem;

  // ---------------- init: build bf16 B-fragments in LDS, prefill states ----
  if (role == 0) {
    float* bi = (float*)(smem + 114944);
    float* bh = (float*)(smem + 115136);
    float* hm = (float*)(smem + 110848);
    for (int p = tid; p < 6144; p += 512) {
      int c = p % 48; int r2 = p / 48; int grp = r2 & 3; int kb = r2 >> 2;
      int g = c >> 4, u = c & 15;
      unsigned short* dst = frag + (kb*3 + g)*512 + (grp*16 + u)*8;
      const float* s = Whh0 + (size_t)(g*H + base + u)*H + kb*32 + grp*8;
      #pragma unroll
      for (int j = 0; j < 8; ++j) dst[j] = f2bf(s[j]);
    }
    if (tid < 48) {
      int g = tid >> 4, u = tid & 15;
      bi[tid] = bih0[g*H + base + u];
      bh[tid] = bhh0[g*H + base + u];
    }
    for (int p = tid; p < 1024; p += 512) {
      int b = p >> 4, u = p & 15;
      float v = z[b*H + base + u];
      hm[p] = v;
      st_u16(&h0buf[65536 + b*H + base + u], f2bf(v));   // y0_{-1} := z
    }
  } else if (role == 1) {
    float* bi = (float*)(smem + 150016);
    float* bh = (float*)(smem + 150112);
    float* hm = (float*)(smem + 147968);
    for (int p = tid; p < 8192; p += 512) {
      int c = p & 31, grp = (p >> 5) & 3, kb = (p >> 7) & 31, gm = p >> 12;
      unsigned short* dst = frag + gm*32768 + (kb*2 + (c>>4))*512 + (grp*16 + (c&15))*8;
      if (c < 24) {
        int g = c >> 3, u = c & 7;
        const float* W = gm ? Whh1 : Wih1;
        const float* s = W + (size_t)(g*H + base + u)*H + kb*32 + grp*8;
        #pragma unroll
        for (int j = 0; j < 8; ++j) dst[j] = f2bf(s[j]);
      } else {
        #pragma unroll
        for (int j = 0; j < 8; ++j) dst[j] = 0;
      }
    }
    if (tid < 24) {
      int g = tid >> 3, u = tid & 7;
      bi[tid] = bih1[g*H + base + u];
      bh[tid] = bhh1[g*H + base + u];
    }
    {
      int b = tid >> 3, u = tid & 7;
      float v = z[b*H + base + u];
      hm[tid] = v;
      st_u16(&h1buf[65536 + b*H + base + u], f2bf(v));   // y1_{-1} := z
    }
  } else {
    float* bo = (float*)(smem + 32768);
    for (int p = tid; p < 2048; p += 512) {
      int c = p & 15, grp = (p >> 4) & 3, kb = p >> 6;
      unsigned short* dst = frag + kb*512 + (grp*16 + c)*8;
      const float* s = Wout + (size_t)(base + c)*H + kb*32 + grp*8;
      #pragma unroll
      for (int j = 0; j < 8; ++j) dst[j] = f2bf(s[j]);
    }
    if (tid < 16) bo[tid] = bout[base + tid];
  }

  unsigned phase = 1;
  bar_worker(ctr, epoch, phase, tid, bid); ++phase;

  // ---------------- pipelined recurrence ----------------
  for (int s = 0; s < 1026; ++s, ++phase) {
    if (role == 0) {
      if (s < 1024) {
        const int t = s;
        float* G  = (float*)(smem + 98304);
        float* hm = (float*)(smem + 110848);
        float* bi = (float*)(smem + 114944);
        float* bh = (float*)(smem + 115136);
        if (w < 4) {   // waves 0-3: one M-tile each, N=48 (3 tiles), K=1024
          const unsigned short* src  = h0buf + ((t+1)&1)*65536;
          const unsigned short* arow = src + (w*16 + (lane&15))*H + ((lane>>4)*8);
          const unsigned short* bb   = frag + lane*8;
          f32x4 a0 = {0,0,0,0}, a1 = {0,0,0,0}, a2 = {0,0,0,0};
          s16x8 A0[16], A1[16];
          GLD16A(A0, arow);
          GLD16B(A1, arow);
          WAITV(16); TIE16(A0);
          #pragma unroll
          for (int i = 0; i < 16; ++i) {
            s16x8 b0 = *(const s16x8*)(bb + (i*3+0)*512);
            s16x8 b1 = *(const s16x8*)(bb + (i*3+1)*512);
            s16x8 b2 = *(const s16x8*)(bb + (i*3+2)*512);
            a0 = __builtin_amdgcn_mfma_f32_16x16x32_bf16(A0[i], b0, a0, 0, 0, 0);
            a1 = __builtin_amdgcn_mfma_f32_16x16x32_bf16(A0[i], b1, a1, 0, 0, 0);
            a2 = __builtin_amdgcn_mfma_f32_16x16x32_bf16(A0[i], b2, a2, 0, 0, 0);
          }
          WAITV(0); TIE16(A1);
          #pragma unroll
          for (int i = 0; i < 16; ++i) {
            int kb = 16 + i;
            s16x8 b0 = *(const s16x8*)(bb + (kb*3+0)*512);
            s16x8 b1 = *(const s16x8*)(bb + (kb*3+1)*512);
            s16x8 b2 = *(const s16x8*)(bb + (kb*3+2)*512);
            a0 = __builtin_amdgcn_mfma_f32_16x16x32_bf16(A1[i], b0, a0, 0, 0, 0);
            a1 = __builtin_amdgcn_mfma_f32_16x16x32_bf16(A1[i], b1, a1, 0, 0, 0);
            a2 = __builtin_amdgcn_mfma_f32_16x16x32_bf16(A1[i], b2, a2, 0, 0, 0);
          }
          int col = lane & 15, r0 = (lane >> 4) * 4;
          #pragma unroll
          for (int r = 0; r < 4; ++r) {
            int brow = w*16 + r0 + r;
            G[brow*49 +      col] = a0[r];
            G[brow*49 + 16 + col] = a1[r];
            G[brow*49 + 32 + col] = a2[r];
          }
        }
        __syncthreads();
        if (tid < 128) {
          int b = tid >> 1, u0 = (tid & 1) * 8;
          s16x8 pk;
          #pragma unroll
          for (int j = 0; j < 8; ++j) {
            int u = u0 + j;
            float hr = G[b*49 + u]      + bh[u];
            float hz = G[b*49 + 16 + u] + bh[16 + u];
            float hn = G[b*49 + 32 + u] + bh[32 + u];
            float r  = sigm(bi[u] + hr);         // gx = b_ih_0 (x==0)
            float zg = sigm(bi[16 + u] + hz);
            float n  = tanhf(bi[32 + u] + r * hn);
            int idx = b*16 + u;
            float hp = hm[idx];
            float hv = (1.f - zg) * n + zg * hp;
            hm[idx] = hv;
            pk[j] = (short)f2bf(hv);
          }
          gst16(pk, &h0buf[(t&1)*65536 + b*H + base + u0]);
        }
      }
    } else if (role == 1) {
      if (s >= 1 && s <= 1024) {
        const int t = s - 1;
        float* Gx = (float*)(smem + 131072);
        float* Gh = (float*)(smem + 139520);
        float* hm = (float*)(smem + 147968);
        float* bi = (float*)(smem + 150016);
        float* bh = (float*)(smem + 150112);
        {
          const int mt  = w & 3;
          const int isx = (w < 4);    // waves 0-3: gx GEMM, 4-7: gh GEMM
          const unsigned short* src  = isx ? (h0buf + (t&1)*65536)
                                           : (h1buf + ((t+1)&1)*65536);
          const unsigned short* arow = src + (mt*16 + (lane&15))*H + ((lane>>4)*8);
          const unsigned short* bb   = frag + (isx ? 0 : 32768) + lane*8;
          f32x4 a0 = {0,0,0,0}, a1 = {0,0,0,0};
          s16x8 A0[16], A1[16];
          GLD16A(A0, arow);
          GLD16B(A1, arow);
          WAITV(16); TIE16(A0);
          #pragma unroll
          for (int i = 0; i < 16; ++i) {
            s16x8 b0 = *(const s16x8*)(bb + (i*2+0)*512);
            s16x8 b1 = *(const s16x8*)(bb + (i*2+1)*512);
            a0 = __builtin_amdgcn_mfma_f32_16x16x32_bf16(A0[i], b0, a0, 0, 0, 0);
            a1 = __builtin_amdgcn_mfma_f32_16x16x32_bf16(A0[i], b1, a1, 0, 0, 0);
          }
          WAITV(0); TIE16(A1);
          #pragma unroll
          for (int i = 0; i < 16; ++i) {
            int kb = 16 + i;
            s16x8 b0 = *(const s16x8*)(bb + (kb*2+0)*512);
            s16x8 b1 = *(const s16x8*)(bb + (kb*2+1)*512);
            a0 = __builtin_amdgcn_mfma_f32_16x16x32_bf16(A1[i], b0, a0, 0, 0, 0);
            a1 = __builtin_amdgcn_mfma_f32_16x16x32_bf16(A1[i], b1, a1, 0, 0, 0);
          }
          float* G = isx ? Gx : Gh;
          int col = lane & 15, r0 = (lane >> 4) * 4;
          #pragma unroll
          for (int r = 0; r < 4; ++r) {
            int brow = mt*16 + r0 + r;
            G[brow*33 +      col] = a0[r];
            G[brow*33 + 16 + col] = a1[r];
          }
        }
        __syncthreads();
        if (tid < 64) {
          int b = tid;
          s16x8 pk;
          #pragma unroll
          for (int u = 0; u < 8; ++u) {
            float xr = Gx[b*33 + u]      + bi[u];
            float xz = Gx[b*33 + 8 + u]  + bi[8 + u];
            float xn = Gx[b*33 + 16 + u] + bi[16 + u];
            float hr = Gh[b*33 + u]      + bh[u];
            float hz = Gh[b*33 + 8 + u]  + bh[8 + u];
            float hn = Gh[b*33 + 16 + u] + bh[16 + u];
            float r  = sigm(xr + hr);
            float zg = sigm(xz + hz);
            float n  = tanhf(xn + r * hn);
            int idx = b*8 + u;
            float hp = hm[idx];
            float hv = (1.f - zg) * n + zg * hp;
            hm[idx] = hv;
            pk[u] = (short)f2bf(hv);
          }
          gst16(pk, &h1buf[(t&1)*65536 + b*H + base]);
        }
      }
    } else {
      if (s >= 2) {
        const int t = s - 2;
        float* bo = (float*)(smem + 32768);
        if (w < 4) {
          const unsigned short* src  = h1buf + (t&1)*65536;
          const unsigned short* arow = src + (w*16 + (lane&15))*H + ((lane>>4)*8);
          const unsigned short* bb   = frag + lane*8;
          f32x4 a0 = {0,0,0,0};
          s16x8 A0[16], A1[16];
          GLD16A(A0, arow);
          GLD16B(A1, arow);
          WAITV(16); TIE16(A0);
          #pragma unroll
          for (int i = 0; i < 16; ++i) {
            s16x8 b0 = *(const s16x8*)(bb + i*512);
            a0 = __builtin_amdgcn_mfma_f32_16x16x32_bf16(A0[i], b0, a0, 0, 0, 0);
          }
          WAITV(0); TIE16(A1);
          #pragma unroll
          for (int i = 0; i < 16; ++i) {
            s16x8 b0 = *(const s16x8*)(bb + (16+i)*512);
            a0 = __builtin_amdgcn_mfma_f32_16x16x32_bf16(A1[i], b0, a0, 0, 0, 0);
          }
          int col = lane & 15, r0 = (lane >> 4) * 4;
          #pragma unroll
          for (int r = 0; r < 4; ++r) {
            int brow = w*16 + r0 + r;
            out[(size_t)(brow*T + t)*128 + base + col] = a0[r] + bo[col];
          }
        }
      }
    }
    bar_worker(ctr, epoch, phase, tid, bid);
  }
}

extern "C" void kernel_launch(void* const* d_in, const int* in_sizes, int n_in,
                              void* d_out, int out_size, void* d_ws, size_t ws_size,
                              hipStream_t stream) {
  const float* z    = (const float*)d_in[0];
  // d_in[1] = seq_len (==1024, hard-coded); d_in[2] = W_ih_0 (unused: x0==0)
  const float* Whh0 = (const float*)d_in[3];
  const float* bih0 = (const float*)d_in[4];
  const float* bhh0 = (const float*)d_in[5];
  const float* Wih1 = (const float*)d_in[6];
  const float* Whh1 = (const float*)d_in[7];
  const float* bih1 = (const float*)d_in[8];
  const float* bhh1 = (const float*)d_in[9];
  const float* Wout = (const float*)d_in[10];
  const float* bout = (const float*)d_in[11];
  float* out = (float*)d_out;

  unsigned* ctr   = (unsigned*)d_ws;                       // 25 x 128B lines
  unsigned* epoch = (unsigned*)((char*)d_ws + 4096);       // own line
  unsigned short* h0buf = (unsigned short*)((char*)d_ws + 8192);
  unsigned short* h1buf = (unsigned short*)((char*)d_ws + 8192 + 2*65536*2);

  hipFuncSetAttribute((const void*)gru_pipeline,
                      hipFuncAttributeMaxDynamicSharedMemorySize, SMEM_BYTES);
  hipMemsetAsync(d_ws, 0, 8192, stream);   // counters + epoch (ws is poisoned)

  void* args[] = { (void*)&z, (void*)&Whh0, (void*)&bih0, (void*)&bhh0,
                   (void*)&Wih1, (void*)&Whh1, (void*)&bih1, (void*)&bhh1,
                   (void*)&Wout, (void*)&bout, (void*)&out,
                   (void*)&h0buf, (void*)&h1buf, (void*)&ctr, (void*)&epoch };
  hipLaunchCooperativeKernel((void*)gru_pipeline, dim3(NBLK), dim3(512),
                             args, SMEM_BYTES, stream);
}